// Round 19
// baseline (111.792 us; speedup 1.0000x reference)
//
#include <hip/hip_runtime.h>
#include <hip/hip_bf16.h>
#include <stdint.h>

// Problem constants
#define B_   2
#define H_   16
#define N_   2048
#define D_   1024
#define DH   64
#define MTOK 4096   // B_*N_

#define LOG2E 1.44269504088896f

typedef __attribute__((ext_vector_type(8)))  short bf16x8;
typedef __attribute__((ext_vector_type(4)))  float f32x4;
typedef __attribute__((ext_vector_type(16))) float f32x16;
typedef __attribute__((ext_vector_type(2)))  unsigned u32x2;
typedef __attribute__((ext_vector_type(4)))  unsigned short us4;

#define VMCNT_ASM(N) asm volatile("s_waitcnt vmcnt(" #N ")" ::: "memory")

static __device__ __forceinline__ unsigned short f2bf(float f) {
    union { float f; unsigned u; } v; v.f = f;
    unsigned r = v.u + 0x7fffu + ((v.u >> 16) & 1u);
    return (unsigned short)(r >> 16);
}

static __device__ __forceinline__ unsigned f2u(float x) {
    union { float f; unsigned u; } v; v.f = x; return v.u;
}
static __device__ __forceinline__ float u2f(unsigned x) {
    union { unsigned u; float f; } v; v.u = x; return v.f;
}

static __device__ __forceinline__ unsigned cvt_pk_bf16(float lo, float hi) {
    unsigned r;
    asm("v_cvt_pk_bf16_f32 %0, %1, %2" : "=v"(r) : "v"(lo), "v"(hi));
    return r;
}

static __device__ __forceinline__ bf16x8 frag_from_u32(unsigned a, unsigned b, unsigned c, unsigned d) {
    union { unsigned u[4]; bf16x8 v; } x;
    x.u[0] = a; x.u[1] = b; x.u[2] = c; x.u[3] = d;
    return x.v;
}

static __device__ __forceinline__ void load_lds16(const void* g, void* l) {
    __builtin_amdgcn_global_load_lds(
        (const __attribute__((address_space(1))) unsigned int*)g,
        (__attribute__((address_space(3))) unsigned int*)l, 16, 0, 0);
}

// ---- fused preprocessing: x fp32->bf16 | W1 transpose | W2 transpose ----
__global__ __launch_bounds__(256) void k_pre(const float* __restrict__ x,
                                             unsigned short* __restrict__ xb,
                                             const float* __restrict__ W1,
                                             unsigned short* __restrict__ w1t,
                                             const float* __restrict__ W2,
                                             unsigned short* __restrict__ w2t) {
    int blk = blockIdx.x;
    int t = threadIdx.x;
    if (blk < 4096) {
        int idx = (blk * 256 + t) * 4;
        float4 v = *(const float4*)(x + idx);
        us4 o;
        o.x = f2bf(v.x); o.y = f2bf(v.y); o.z = f2bf(v.z); o.w = f2bf(v.w);
        *(us4*)(xb + idx) = o;
        return;
    }
    const float* in;
    unsigned short* out;
    int C, bx, by;
    if (blk < 4864) { in = W1; out = w1t; C = 3072; int b2 = blk - 4096; bx = b2 % 48; by = b2 / 48; }
    else            { in = W2; out = w2t; C = 1024; int b2 = blk - 4864; bx = b2 % 16; by = b2 / 16; }
    const int R = 1024;
    __shared__ float tile[64][65];
    int c0 = bx * 64, r0 = by * 64;
    int tr = t >> 4, tc = (t & 15) * 4;
#pragma unroll
    for (int p = 0; p < 4; p++) {
        int row = p * 16 + tr;
        float4 v = *(const float4*)(in + (size_t)(r0 + row) * C + c0 + tc);
        tile[row][tc + 0] = v.x; tile[row][tc + 1] = v.y;
        tile[row][tc + 2] = v.z; tile[row][tc + 3] = v.w;
    }
    __syncthreads();
    int oc = t >> 4, orr = (t & 15) * 4;
#pragma unroll
    for (int p = 0; p < 4; p++) {
        int crow = p * 16 + oc;
        us4 o;
        o.x = f2bf(tile[orr + 0][crow]);
        o.y = f2bf(tile[orr + 1][crow]);
        o.z = f2bf(tile[orr + 2][crow]);
        o.w = f2bf(tile[orr + 3][crow]);
        *(us4*)(out + (size_t)(c0 + crow) * R + r0 + orr) = o;
    }
}

// ======== k_gemm0: 256x192 tile, BK=64, merged phases (4 barriers/K-tile) ========
__global__ __launch_bounds__(512, 2) void k_gemm0(const unsigned short* __restrict__ A,
                                                  const unsigned short* __restrict__ Bt,
                                                  const float* __restrict__ bias,
                                                  unsigned short* __restrict__ qdst,
                                                  unsigned short* __restrict__ kdst,
                                                  unsigned short* __restrict__ vdst) {
    __shared__ unsigned short lds[57344];   // A0 @0, A1 @16384, B0 @32768, B1 @45056 (elems)
    const int K = 1024, NT = 16;
    int tid = threadIdx.x;
    int lane = tid & 63, wv = tid >> 6;       // 8 waves
    int wm = wv >> 2, wn = wv & 3;            // 2 x 4
    int F = blockIdx.x;
    int L = (F & 7) * 32 + (F >> 3);
    int n0 = (L % 16) * 192;
    int m0 = (L / 16) * 256;

    f32x4 acc[8][3];
#pragma unroll
    for (int i = 0; i < 8; i++)
#pragma unroll
        for (int j = 0; j < 3; j++) {
            f32x4 z; z[0] = 0.f; z[1] = 0.f; z[2] = 0.f; z[3] = 0.f;
            acc[i][j] = z;
        }

    auto stage = [&](int t) {
        int p = t & 1;
        int k0 = t * 64;
        unsigned short* ab = &lds[p * 16384];
        unsigned short* bb = &lds[32768 + p * 12288];
#pragma unroll
        for (int i = 0; i < 4; i++) {
            int u = i * 512 + tid;
            int r = u >> 3, c8 = u & 7;
            int c8s = c8 ^ (r & 7);
            int db = (i * 512 + wv * 64) * 8;
            load_lds16(A + (size_t)(m0 + r) * K + k0 + c8s * 8, &ab[db]);
            if (i < 3)
                load_lds16(Bt + (size_t)(n0 + r) * K + k0 + c8s * 8, &bb[db]);
        }
    };

    stage(0);
    stage(1);

    const int ml = lane & 15, ul = lane >> 4;
    bf16x8 afr[8], bfr[3];

#pragma unroll 1
    for (int t = 0; t < NT; ++t) {
        if (t < NT - 1) { VMCNT_ASM(7); }
        else            { VMCNT_ASM(0); }
        __builtin_amdgcn_s_barrier();

        const unsigned short* ab = &lds[(t & 1) * 16384];
        const unsigned short* bb = &lds[32768 + (t & 1) * 12288];

#pragma unroll
        for (int kk = 0; kk < 2; ++kk) {
            int ck = ((kk * 4 + ul) ^ (ml & 7)) * 8;
#pragma unroll
            for (int nj = 0; nj < 3; nj++)
                bfr[nj] = *(const bf16x8*)&bb[(wn * 48 + nj * 16 + ml) * 64 + ck];
#pragma unroll
            for (int q = 0; q < 8; q++)
                afr[q] = *(const bf16x8*)&ab[(wm * 128 + q * 16 + ml) * 64 + ck];
            __builtin_amdgcn_s_barrier();
            __builtin_amdgcn_s_setprio(1);
#pragma unroll
            for (int q = 0; q < 8; q++)
#pragma unroll
                for (int nj = 0; nj < 3; nj++)
                    acc[q][nj] = __builtin_amdgcn_mfma_f32_16x16x32_bf16(
                        afr[q], bfr[nj], acc[q][nj], 0, 0, 0);
            __builtin_amdgcn_s_setprio(0);
            __builtin_amdgcn_s_barrier();
        }
        if (t + 2 < NT) stage(t + 2);
    }

    // epilogue  (C/D: col = lane&15, row = (lane>>4)*4 + r)
#pragma unroll
    for (int nj = 0; nj < 3; nj++) {
        int col = n0 + wn * 48 + nj * 16 + (lane & 15);
        float bv = bias[col];
        int which = col >> 10;
        int hd = (col >> 6) & 15;
        int dh = col & 63;
        float scl = (which == 0) ? (0.125f * LOG2E) : 1.0f;
#pragma unroll
        for (int mi = 0; mi < 8; mi++) {
            int rbase = m0 + wm * 128 + mi * 16 + (lane >> 4) * 4;
#pragma unroll
            for (int r = 0; r < 4; r++) {
                int tok = rbase + r;
                int bb2 = tok >> 11, nn = tok & 2047;
                float vvv = (acc[mi][nj][r] + bv) * scl;
                size_t chunk = ((size_t)(bb2 * H_ + hd) * 64 + (nn >> 5)) * 2048;
                if (which == 0) {
                    qdst[((size_t)(bb2 * H_ + hd) * N_ + nn) * DH + dh] = f2bf(vvv);
                } else if (which == 1) {
                    int lane2 = ((dh >> 3) & 1) * 32 + (nn & 31);
                    kdst[chunk + (dh >> 4) * 512 + lane2 * 8 + (dh & 7)] = f2bf(vvv);
                } else {
                    int lane2 = ((nn >> 3) & 1) * 32 + (dh & 31);
                    int islot = (dh >> 5) * 2 + ((nn >> 4) & 1);
                    vdst[chunk + islot * 512 + lane2 * 8 + (nn & 7)] = f2bf(vvv);
                }
            }
        }
    }
}

// ======== k_gemm1: 128x128 tile, BK=64, deep-phase schedule (gemm0 template) ========
__global__ __launch_bounds__(512, 2) void k_gemm1(const unsigned short* __restrict__ A,
                                                  const unsigned short* __restrict__ Bt,
                                                  const float* __restrict__ bias,
                                                  float* __restrict__ outp) {
    __shared__ unsigned short lds1[32768];  // A0 @0, A1 @8192, B0 @16384, B1 @24576 (elems)
    const int K = 1024, NT = 16;
    int tid = threadIdx.x;
    int lane = tid & 63, wv = tid >> 6;
    int wm = wv >> 2, wn = wv & 3;            // 2 x 4
    int F = blockIdx.x;
    int L = (F & 7) * 32 + (F >> 3);
    int n0 = (L % 8) * 128;
    int m0 = (L / 8) * 128;
    int bIdx = m0 >> 11;
    int ntok0 = m0 & 2047;

    f32x4 acc[4][2];
#pragma unroll
    for (int i = 0; i < 4; i++)
#pragma unroll
        for (int j = 0; j < 2; j++) {
            f32x4 z; z[0] = 0.f; z[1] = 0.f; z[2] = 0.f; z[3] = 0.f;
            acc[i][j] = z;
        }

    auto stage = [&](int t) {                  // k-tile t == head t
        int p = t & 1;
        const unsigned short* aptr = A + ((size_t)(bIdx * H_ + t) * N_ + ntok0) * DH;
        const unsigned short* bptr = Bt + (size_t)n0 * K + t * 64;
        unsigned short* ab = &lds1[p * 8192];
        unsigned short* bb = &lds1[16384 + p * 8192];
#pragma unroll
        for (int i = 0; i < 2; i++) {
            int u = i * 512 + tid;
            int r = u >> 3, c8 = u & 7;
            int c8s = c8 ^ (r & 7);
            int db = (i * 512 + wv * 64) * 8;
            load_lds16(aptr + (size_t)r * DH + c8s * 8, &ab[db]);
            load_lds16(bptr + (size_t)r * K  + c8s * 8, &bb[db]);
        }
    };

    stage(0);
    stage(1);

    const int ml = lane & 15, ul = lane >> 4;
    bf16x8 afr[4], bfr[2];

#pragma unroll 1
    for (int t = 0; t < NT; ++t) {
        if (t < NT - 1) { VMCNT_ASM(4); }
        else            { VMCNT_ASM(0); }
        __builtin_amdgcn_s_barrier();

        const unsigned short* ab = &lds1[(t & 1) * 8192];
        const unsigned short* bb = &lds1[16384 + (t & 1) * 8192];

#pragma unroll
        for (int kk = 0; kk < 2; ++kk) {
            int ck = ((kk * 4 + ul) ^ (ml & 7)) * 8;
#pragma unroll
            for (int nj = 0; nj < 2; nj++)
                bfr[nj] = *(const bf16x8*)&bb[(wn * 32 + nj * 16 + ml) * 64 + ck];
#pragma unroll
            for (int q = 0; q < 4; q++)
                afr[q] = *(const bf16x8*)&ab[(wm * 64 + q * 16 + ml) * 64 + ck];
            __builtin_amdgcn_s_barrier();
            __builtin_amdgcn_s_setprio(1);
#pragma unroll
            for (int q = 0; q < 4; q++)
#pragma unroll
                for (int nj = 0; nj < 2; nj++)
                    acc[q][nj] = __builtin_amdgcn_mfma_f32_16x16x32_bf16(
                        afr[q], bfr[nj], acc[q][nj], 0, 0, 0);
            __builtin_amdgcn_s_setprio(0);
            __builtin_amdgcn_s_barrier();
        }
        if (t + 2 < NT) stage(t + 2);
    }

    // epilogue  (C/D: col = lane&15, row = (lane>>4)*4 + r)
#pragma unroll
    for (int nj = 0; nj < 2; nj++) {
        int col = n0 + wn * 32 + nj * 16 + ml;
        float bv = bias[col];
#pragma unroll
        for (int mi = 0; mi < 4; mi++) {
            int rbase = m0 + wm * 64 + mi * 16 + (lane >> 4) * 4;
#pragma unroll
            for (int r = 0; r < 4; r++)
                outp[(size_t)(rbase + r) * D_ + col] = acc[mi][nj][r] + bv;
        }
    }
}

// ------- flash attention: 64 q-rows/wave (2 independent Q-groups), KVBLK=64 -------
// Block: 256 thr = 4 waves = 2 qsub (64 rows each) x 2 kvh (1024 kv each).
// 16 tiles of 64 kv per half (r18's bug: loop ran 32 tiles, 2x overrun).
// Staging roles: wv0 -> K-h0, wv1 -> K-h1, wv2 -> V-h0, wv3 -> V-h1 (ring-2).
// LDS 64KB -> 2 blocks/CU; grid 512 (32 bh x 16 q-tiles of 128 rows).
__global__ __launch_bounds__(256, 2) void k_attn(const unsigned short* __restrict__ qh,
                                                 const unsigned short* __restrict__ ks,
                                                 const unsigned short* __restrict__ vs,
                                                 unsigned short* __restrict__ o) {
    __shared__ unsigned short smem[32768];   // 64 KB: K[2h][2r][4096] | V[2h][2r][4096]
    unsigned short* kb = smem;               // kb + half*8192 + ring*4096
    unsigned short* vb = smem + 16384;
    float* red = (float*)smem;               // reused for merge (34816 B)

    int tid = threadIdx.x;
    int lane = tid & 63, wv = tid >> 6;      // wv 0..3
    int qsub = wv >> 1;                      // 0..1 (64-row half)
    int kvh  = wv & 1;                       // 0..1
    int F = blockIdx.x;
    int L = (F & 7) * 64 + (F >> 3);
    int bh = L >> 4;
    int q0 = (L & 15) * 128 + qsub * 64;
    int ln = lane & 31, hi = lane >> 5;
    const size_t bhO = (size_t)bh * N_ * DH;

    // Q fragments for the two 32-row groups
    const unsigned short* qp = qh + bhO;
    bf16x8 qf0[4], qf1[4];
#pragma unroll
    for (int kk = 0; kk < 4; kk++) {
        qf0[kk] = *(const bf16x8*)(qp + (size_t)(q0 + ln) * DH + kk * 16 + hi * 8);
        qf1[kk] = *(const bf16x8*)(qp + (size_t)(q0 + 32 + ln) * DH + kk * 16 + hi * 8);
    }

    const unsigned short* kg = ks + (size_t)bh * 131072;
    const unsigned short* vg = vs + (size_t)bh * 131072;

    // staging: wv0 K-h0, wv1 K-h1, wv2 V-h0, wv3 V-h1; 8 gload_lds per tile
    int sh = wv & 1;
    unsigned short* dstb = ((wv >> 1) ? vb : kb) + sh * 8192;
    const unsigned short* srcb = ((wv >> 1) ? vg : kg) + (size_t)sh * 65536;
    auto stageT = [&](int ring, int t) {
#pragma unroll
        for (int i = 0; i < 8; i++)
            load_lds16(srcb + (size_t)t * 4096 + i * 512 + lane * 8,
                       dstb + ring * 4096 + i * 512);
    };

    f32x16 o00, o01, o10, o11;
#pragma unroll
    for (int r = 0; r < 16; r++) { o00[r] = 0.f; o01[r] = 0.f; o10[r] = 0.f; o11[r] = 0.f; }
    float m0v = -INFINITY, l0v = 0.f, m1v = -INFINITY, l1v = 0.f;

    // softmax + pack for one group: consumes sa/sb, updates (m,l,oA,oB), emits pf[4]
    auto smax = [&](const f32x16& sa, const f32x16& sb, float& m, float& l,
                    f32x16& oA, f32x16& oB, bf16x8* pf) {
        float mx[8];
#pragma unroll
        for (int i = 0; i < 8; i++)
            mx[i] = fmaxf(fmaxf(sa[i], sa[i + 8]), fmaxf(sb[i], sb[i + 8]));
#pragma unroll
        for (int i = 0; i < 4; i++) mx[i] = fmaxf(mx[i], mx[i + 4]);
        float mt = fmaxf(fmaxf(mx[0], mx[2]), fmaxf(mx[1], mx[3]));
        {
            u32x2 sw = __builtin_amdgcn_permlane32_swap(f2u(mt), f2u(mt), false, false);
            mt = fmaxf(u2f(sw[0]), u2f(sw[1]));
        }
        if (!__all(mt <= m + 8.0f)) {   // defer-max: p <= 2^8
            float mn = fmaxf(m, mt);
            float fs = __builtin_amdgcn_exp2f(m - mn);
            m = mn;
            l *= fs;
#pragma unroll
            for (int r = 0; r < 16; r++) { oA[r] *= fs; oB[r] *= fs; }
        }
        float pa[16], pb[16];
#pragma unroll
        for (int r = 0; r < 16; r++) {
            pa[r] = __builtin_amdgcn_exp2f(sa[r] - m);
            pb[r] = __builtin_amdgcn_exp2f(sb[r] - m);
        }
        float sm[8];
#pragma unroll
        for (int i = 0; i < 8; i++) sm[i] = (pa[i] + pa[i + 8]) + (pb[i] + pb[i + 8]);
#pragma unroll
        for (int i = 0; i < 4; i++) sm[i] = sm[i] + sm[i + 4];
        float sum = (sm[0] + sm[2]) + (sm[1] + sm[3]);
        {
            u32x2 sw = __builtin_amdgcn_permlane32_swap(f2u(sum), f2u(sum), false, false);
            sum = u2f(sw[0]) + u2f(sw[1]);
        }
        l += sum;

        unsigned pka[8], pkb[8];
#pragma unroll
        for (int i = 0; i < 8; i++) {
            pka[i] = cvt_pk_bf16(pa[2 * i], pa[2 * i + 1]);
            pkb[i] = cvt_pk_bf16(pb[2 * i], pb[2 * i + 1]);
        }
        u32x2 s0 = __builtin_amdgcn_permlane32_swap(pka[0], pka[2], false, false);
        u32x2 s1 = __builtin_amdgcn_permlane32_swap(pka[1], pka[3], false, false);
        u32x2 s2 = __builtin_amdgcn_permlane32_swap(pka[4], pka[6], false, false);
        u32x2 s3 = __builtin_amdgcn_permlane32_swap(pka[5], pka[7], false, false);
        pf[0] = frag_from_u32(s0[0], s1[0], s0[1], s1[1]);  // kv  0..15
        pf[1] = frag_from_u32(s2[0], s3[0], s2[1], s3[1]);  // kv 16..31
        s0 = __builtin_amdgcn_permlane32_swap(pkb[0], pkb[2], false, false);
        s1 = __builtin_amdgcn_permlane32_swap(pkb[1], pkb[3], false, false);
        s2 = __builtin_amdgcn_permlane32_swap(pkb[4], pkb[6], false, false);
        s3 = __builtin_amdgcn_permlane32_swap(pkb[5], pkb[7], false, false);
        pf[2] = frag_from_u32(s0[0], s1[0], s0[1], s1[1]);  // kv 32..47
        pf[3] = frag_from_u32(s2[0], s3[0], s2[1], s3[1]);  // kv 48..63
    };

    stageT(0, 0);
    __syncthreads();

#pragma unroll 1
    for (int t = 0; t < 16; ++t) {
        int b = t & 1;
        if (t < 15) stageT(b ^ 1, t + 1);

        const unsigned short* kB = kb + kvh * 8192 + b * 4096;
        const unsigned short* vB = vb + kvh * 8192 + b * 4096;

        // ---- QK^T for both groups (shared K fragments) ----
        bf16x8 kfa[4], kfb[4];
#pragma unroll
        for (int i = 0; i < 4; i++) {
            kfa[i] = *(const bf16x8*)&kB[i * 512 + lane * 8];
            kfb[i] = *(const bf16x8*)&kB[2048 + i * 512 + lane * 8];
        }
        f32x16 sa0, sb0, sa1, sb1;
#pragma unroll
        for (int r = 0; r < 16; r++) { sa0[r] = 0.f; sb0[r] = 0.f; sa1[r] = 0.f; sb1[r] = 0.f; }
#pragma unroll
        for (int i = 0; i < 4; i++) {
            sa0 = __builtin_amdgcn_mfma_f32_32x32x16_bf16(kfa[i], qf0[i], sa0, 0, 0, 0);
            sa1 = __builtin_amdgcn_mfma_f32_32x32x16_bf16(kfa[i], qf1[i], sa1, 0, 0, 0);
        }
#pragma unroll
        for (int i = 0; i < 4; i++) {
            sb0 = __builtin_amdgcn_mfma_f32_32x32x16_bf16(kfb[i], qf0[i], sb0, 0, 0, 0);
            sb1 = __builtin_amdgcn_mfma_f32_32x32x16_bf16(kfb[i], qf1[i], sb1, 0, 0, 0);
        }

        // ---- softmax + pack, two independent chains ----
        bf16x8 pf0[4], pf1[4];
        smax(sa0, sb0, m0v, l0v, o00, o01, pf0);
        smax(sa1, sb1, m1v, l1v, o10, o11, pf1);

        // ---- PV: shared V fragments, both groups ----
        bf16x8 vf0 = *(const bf16x8*)&vB[0 * 512 + lane * 8];          // d 0..31, kv 0..15
        bf16x8 vf1 = *(const bf16x8*)&vB[1 * 512 + lane * 8];          // d 0..31, kv16..31
        bf16x8 vf2 = *(const bf16x8*)&vB[2048 + 0 * 512 + lane * 8];   // d 0..31, kv32..47
        bf16x8 vf3 = *(const bf16x8*)&vB[2048 + 1 * 512 + lane * 8];   // d 0..31, kv48..63
        o00 = __builtin_amdgcn_mfma_f32_32x32x16_bf16(vf0, pf0[0], o00, 0, 0, 0);
        o10 = __builtin_amdgcn_mfma_f32_32x32x16_bf16(vf0, pf1[0], o10, 0, 0, 0);
        o00 = __builtin_amdgcn_mfma_f32_32x32x16_bf16(vf1, pf0[1], o00, 0, 0, 0);
        o10 = __builtin_amdgcn_mfma_f32_32x32x16_bf16(vf1, pf1[1], o10, 0, 0, 0);
        o00 = __builtin_amdgcn_mfma_f32_32x32x16_bf16(vf2, pf0[2], o00, 0, 0, 0);
        o10 = __builtin_amdgcn_mfma_f32_32x32x16_bf16(vf2, pf1[2], o10, 0, 0, 0);
        o00 = __builtin_amdgcn_mfma_f32_32x32x16_bf16(vf3, pf0[3], o00, 0, 0, 0);
        o10 = __builtin_amdgcn_mfma_f32_32x32x16_bf16(vf3, pf1[3], o10, 0, 0, 0);
        vf0 = *(const bf16x8*)&vB[2 * 512 + lane * 8];                 // d32..63, kv 0..15
        vf1 = *(const bf16x8*)&vB[3 * 512 + lane * 8];                 // d32..63, kv16..31
        vf2 = *(const bf16x8*)&vB[2048 + 2 * 512 + lane * 8];          // d32..63, kv32..47
        vf3 = *(const bf16x8*)&vB[2048 + 3 * 512 + lane * 8];          // d32..63, kv48..63
        o01 = __builtin_amdgcn_mfma_f32_32x32x16_bf16(vf0, pf0[0], o01, 0, 0, 0);
        o11 = __builtin_amdgcn_mfma_f32_32x32x16_bf16(vf0, pf1[0], o11, 0, 0, 0);
        o01 = __builtin_amdgcn_mfma_f32_32x32x16_bf16(vf1, pf0[1], o01, 0, 0, 0);
        o11 = __builtin_amdgcn_mfma_f32_32x32x16_bf16(vf1, pf1[1], o11, 0, 0, 0);
        o01 = __builtin_amdgcn_mfma_f32_32x32x16_bf16(vf2, pf0[2], o01, 0, 0, 0);
        o11 = __builtin_amdgcn_mfma_f32_32x32x16_bf16(vf2, pf1[2], o11, 0, 0, 0);
        o01 = __builtin_amdgcn_mfma_f32_32x32x16_bf16(vf3, pf0[3], o01, 0, 0, 0);
        o11 = __builtin_amdgcn_mfma_f32_32x32x16_bf16(vf3, pf1[3], o11, 0, 0, 0);

        __syncthreads();   // stage(t+1) landed + all reads of ring b done
    }

    // ---- merge kv-halves via LDS (exp-weighted, r3-validated); 2 groups/wave ----
    if (kvh == 1) {
#pragma unroll
        for (int g = 0; g < 2; g++) {
            float* rp = red + ((qsub * 2 + g) * 64 + lane) * 34;
            const f32x16& oa = g ? o10 : o00;
            const f32x16& ob2 = g ? o11 : o01;
#pragma unroll
            for (int r = 0; r < 16; r++) { rp[r] = oa[r]; rp[16 + r] = ob2[r]; }
            rp[32] = g ? m1v : m0v;
            rp[33] = g ? l1v : l0v;
        }
    }
    __syncthreads();
    if (kvh == 0) {
#pragma unroll
        for (int g = 0; g < 2; g++) {
            const float* rp = red + ((qsub * 2 + g) * 64 + lane) * 34;
            float m = g ? m1v : m0v, l = g ? l1v : l0v;
            const f32x16& oa = g ? o10 : o00;
            const f32x16& ob2 = g ? o11 : o01;
            float mb = rp[32], lb = rp[33];
            float mn = fmaxf(m, mb);
            float fa = __builtin_amdgcn_exp2f(m - mn);
            float fb = __builtin_amdgcn_exp2f(mb - mn);
            float inv = 1.0f / (l * fa + lb * fb);
            float ga = fa * inv, gb = fb * inv;
            unsigned short* ob = o + bhO + (size_t)(q0 + g * 32 + ln) * DH;
#pragma unroll
            for (int t2 = 0; t2 < 2; t2++) {
#pragma unroll
                for (int gg = 0; gg < 4; gg++) {
                    int d = t2 * 32 + gg * 8 + hi * 4;   // rows: (r&3)+8*(r>>2)+4*hi
                    int rb = gg * 4;
                    float a0 = (t2 ? ob2[rb + 0] : oa[rb + 0]) * ga + rp[t2 * 16 + rb + 0] * gb;
                    float a1 = (t2 ? ob2[rb + 1] : oa[rb + 1]) * ga + rp[t2 * 16 + rb + 1] * gb;
                    float a2 = (t2 ? ob2[rb + 2] : oa[rb + 2]) * ga + rp[t2 * 16 + rb + 2] * gb;
                    float a3 = (t2 ? ob2[rb + 3] : oa[rb + 3]) * ga + rp[t2 * 16 + rb + 3] * gb;
                    us4 w;
                    w.x = f2bf(a0); w.y = f2bf(a1); w.z = f2bf(a2); w.w = f2bf(a3);
                    *(us4*)(ob + d) = w;
                }
            }
        }
    }
}

extern "C" void kernel_launch(void* const* d_in, const int* in_sizes, int n_in,
                              void* d_out, int out_size, void* d_ws, size_t ws_size,
                              hipStream_t stream) {
    const float* x  = (const float*)d_in[0];
    const float* W1 = (const float*)d_in[1];
    const float* b1 = (const float*)d_in[2];
    const float* W2 = (const float*)d_in[3];
    const float* b2 = (const float*)d_in[4];
    float* out = (float*)d_out;

    char* ws = (char*)d_ws;
    unsigned short* xb   = (unsigned short*)(ws);                  //  8,388,608 B
    unsigned short* w1t  = (unsigned short*)(ws + 8388608);        //  6,291,456 B
    unsigned short* w2t  = (unsigned short*)(ws + 14680064);       //  2,097,152 B
    unsigned short* qh   = (unsigned short*)(ws + 16777216);       //  8,388,608 B
    unsigned short* ks   = (unsigned short*)(ws + 25165824);       //  8,388,608 B
    unsigned short* vsb  = (unsigned short*)(ws + 33554432);       //  8,388,608 B
    unsigned short* attn = (unsigned short*)(ws + 41943040);       //  8,388,608 B

    k_pre<<<5120, 256, 0, stream>>>(x, xb, W1, w1t, W2, w2t);
    k_gemm0<<<256, 512, 0, stream>>>(xb, w1t, b1, qh, ks, vsb);
    k_attn<<<512, 256, 0, stream>>>(qh, ks, vsb, attn);
    k_gemm1<<<256, 512, 0, stream>>>(attn, w2t, b2, out);
}

// Round 20
// 108.519 us; speedup vs baseline: 1.0302x; 1.0302x over previous
//
#include <hip/hip_runtime.h>
#include <hip/hip_bf16.h>
#include <stdint.h>

// Problem constants
#define B_   2
#define H_   16
#define N_   2048
#define D_   1024
#define DH   64
#define MTOK 4096   // B_*N_

#define LOG2E 1.44269504088896f

typedef __attribute__((ext_vector_type(8)))  short bf16x8;
typedef __attribute__((ext_vector_type(4)))  float f32x4;
typedef __attribute__((ext_vector_type(16))) float f32x16;
typedef __attribute__((ext_vector_type(2)))  unsigned u32x2;
typedef __attribute__((ext_vector_type(4)))  unsigned short us4;

#define VMCNT_ASM(N) asm volatile("s_waitcnt vmcnt(" #N ")" ::: "memory")

static __device__ __forceinline__ unsigned short f2bf(float f) {
    union { float f; unsigned u; } v; v.f = f;
    unsigned r = v.u + 0x7fffu + ((v.u >> 16) & 1u);
    return (unsigned short)(r >> 16);
}

static __device__ __forceinline__ unsigned f2u(float x) {
    union { float f; unsigned u; } v; v.f = x; return v.u;
}
static __device__ __forceinline__ float u2f(unsigned x) {
    union { unsigned u; float f; } v; v.u = x; return v.f;
}

static __device__ __forceinline__ unsigned cvt_pk_bf16(float lo, float hi) {
    unsigned r;
    asm("v_cvt_pk_bf16_f32 %0, %1, %2" : "=v"(r) : "v"(lo), "v"(hi));
    return r;
}

static __device__ __forceinline__ bf16x8 frag_from_u32(unsigned a, unsigned b, unsigned c, unsigned d) {
    union { unsigned u[4]; bf16x8 v; } x;
    x.u[0] = a; x.u[1] = b; x.u[2] = c; x.u[3] = d;
    return x.v;
}

static __device__ __forceinline__ void load_lds16(const void* g, void* l) {
    __builtin_amdgcn_global_load_lds(
        (const __attribute__((address_space(1))) unsigned int*)g,
        (__attribute__((address_space(3))) unsigned int*)l, 16, 0, 0);
}

// ---- fused preprocessing: x fp32->bf16 | W1 transpose | W2 transpose ----
__global__ __launch_bounds__(256) void k_pre(const float* __restrict__ x,
                                             unsigned short* __restrict__ xb,
                                             const float* __restrict__ W1,
                                             unsigned short* __restrict__ w1t,
                                             const float* __restrict__ W2,
                                             unsigned short* __restrict__ w2t) {
    int blk = blockIdx.x;
    int t = threadIdx.x;
    if (blk < 4096) {
        int idx = (blk * 256 + t) * 4;
        float4 v = *(const float4*)(x + idx);
        us4 o;
        o.x = f2bf(v.x); o.y = f2bf(v.y); o.z = f2bf(v.z); o.w = f2bf(v.w);
        *(us4*)(xb + idx) = o;
        return;
    }
    const float* in;
    unsigned short* out;
    int C, bx, by;
    if (blk < 4864) { in = W1; out = w1t; C = 3072; int b2 = blk - 4096; bx = b2 % 48; by = b2 / 48; }
    else            { in = W2; out = w2t; C = 1024; int b2 = blk - 4864; bx = b2 % 16; by = b2 / 16; }
    const int R = 1024;
    __shared__ float tile[64][65];
    int c0 = bx * 64, r0 = by * 64;
    int tr = t >> 4, tc = (t & 15) * 4;
#pragma unroll
    for (int p = 0; p < 4; p++) {
        int row = p * 16 + tr;
        float4 v = *(const float4*)(in + (size_t)(r0 + row) * C + c0 + tc);
        tile[row][tc + 0] = v.x; tile[row][tc + 1] = v.y;
        tile[row][tc + 2] = v.z; tile[row][tc + 3] = v.w;
    }
    __syncthreads();
    int oc = t >> 4, orr = (t & 15) * 4;
#pragma unroll
    for (int p = 0; p < 4; p++) {
        int crow = p * 16 + oc;
        us4 o;
        o.x = f2bf(tile[orr + 0][crow]);
        o.y = f2bf(tile[orr + 1][crow]);
        o.z = f2bf(tile[orr + 2][crow]);
        o.w = f2bf(tile[orr + 3][crow]);
        *(us4*)(out + (size_t)(c0 + crow) * R + r0 + orr) = o;
    }
}

// ======== k_gemm0: 128x128 tile, BK=64 (gemm1 template, 2 blocks/CU) ========
// gemm1's proven structure (780 TF) applied to the QKV GEMM: 64KB LDS ->
// 2 resident blocks/CU (phase-offset execution vs the old 1-block 256x192).
// Grid 768 = 32 m-tiles x 24 n-tiles, bijective XCD swizzle (CPX=96).
// Epilogue: MODE-0 scatter (+b1; q*0.125*log2e -> qh; k/v frag-interleaved).
__global__ __launch_bounds__(512, 2) void k_gemm0(const unsigned short* __restrict__ A,
                                                  const unsigned short* __restrict__ Bt,
                                                  const float* __restrict__ bias,
                                                  unsigned short* __restrict__ qdst,
                                                  unsigned short* __restrict__ kdst,
                                                  unsigned short* __restrict__ vdst) {
    __shared__ unsigned short lds0[32768];  // A0 @0, A1 @8192, B0 @16384, B1 @24576 (elems)
    const int K = 1024, NT = 16;
    int tid = threadIdx.x;
    int lane = tid & 63, wv = tid >> 6;
    int wm = wv >> 2, wn = wv & 3;            // 2 x 4
    int F = blockIdx.x;
    int L = (F & 7) * 96 + (F >> 3);          // 768 blocks
    int n0 = (L % 24) * 128;
    int m0 = (L / 24) * 128;

    f32x4 acc[4][2];
#pragma unroll
    for (int i = 0; i < 4; i++)
#pragma unroll
        for (int j = 0; j < 2; j++) {
            f32x4 z; z[0] = 0.f; z[1] = 0.f; z[2] = 0.f; z[3] = 0.f;
            acc[i][j] = z;
        }

    auto stage = [&](int t) {
        int p = t & 1;
        int k0 = t * 64;
        unsigned short* ab = &lds0[p * 8192];
        unsigned short* bb = &lds0[16384 + p * 8192];
#pragma unroll
        for (int i = 0; i < 2; i++) {
            int u = i * 512 + tid;             // unit = 8 bf16; 1024 units = 128r x 8c8
            int r = u >> 3, c8 = u & 7;
            int c8s = c8 ^ (r & 7);            // inverse (=same) swizzle on SOURCE
            int db = (i * 512 + wv * 64) * 8;  // wave-uniform linear LDS dest
            load_lds16(A  + (size_t)(m0 + r) * K + k0 + c8s * 8, &ab[db]);
            load_lds16(Bt + (size_t)(n0 + r) * K + k0 + c8s * 8, &bb[db]);
        }
    };

    stage(0);
    stage(1);

    const int ml = lane & 15, ul = lane >> 4;
    bf16x8 afr[4], bfr[2];

#pragma unroll 1
    for (int t = 0; t < NT; ++t) {
        if (t < NT - 1) { VMCNT_ASM(4); }
        else            { VMCNT_ASM(0); }
        __builtin_amdgcn_s_barrier();

        const unsigned short* ab = &lds0[(t & 1) * 8192];
        const unsigned short* bb = &lds0[16384 + (t & 1) * 8192];

#pragma unroll
        for (int kk = 0; kk < 2; ++kk) {
            int ck = ((kk * 4 + ul) ^ (ml & 7)) * 8;
#pragma unroll
            for (int nj = 0; nj < 2; nj++)
                bfr[nj] = *(const bf16x8*)&bb[(wn * 32 + nj * 16 + ml) * 64 + ck];
#pragma unroll
            for (int q = 0; q < 4; q++)
                afr[q] = *(const bf16x8*)&ab[(wm * 64 + q * 16 + ml) * 64 + ck];
            __builtin_amdgcn_s_barrier();
            __builtin_amdgcn_s_setprio(1);
#pragma unroll
            for (int q = 0; q < 4; q++)
#pragma unroll
                for (int nj = 0; nj < 2; nj++)
                    acc[q][nj] = __builtin_amdgcn_mfma_f32_16x16x32_bf16(
                        afr[q], bfr[nj], acc[q][nj], 0, 0, 0);
            __builtin_amdgcn_s_setprio(0);
            __builtin_amdgcn_s_barrier();
        }
        if (t + 2 < NT) stage(t + 2);
    }

    // epilogue  (C/D: col = lane&15, row = (lane>>4)*4 + r) — verified scatter
#pragma unroll
    for (int nj = 0; nj < 2; nj++) {
        int col = n0 + wn * 32 + nj * 16 + ml;
        float bv = bias[col];
        int which = col >> 10;
        int hd = (col >> 6) & 15;
        int dh = col & 63;
        float scl = (which == 0) ? (0.125f * LOG2E) : 1.0f;
#pragma unroll
        for (int mi = 0; mi < 4; mi++) {
            int rbase = m0 + wm * 64 + mi * 16 + (lane >> 4) * 4;
#pragma unroll
            for (int r = 0; r < 4; r++) {
                int tok = rbase + r;
                int bb2 = tok >> 11, nn = tok & 2047;
                float vvv = (acc[mi][nj][r] + bv) * scl;
                size_t chunk = ((size_t)(bb2 * H_ + hd) * 64 + (nn >> 5)) * 2048;
                if (which == 0) {
                    qdst[((size_t)(bb2 * H_ + hd) * N_ + nn) * DH + dh] = f2bf(vvv);
                } else if (which == 1) {
                    // K fragment-INTERLEAVED: [frag][lane][8el]
                    int lane2 = ((dh >> 3) & 1) * 32 + (nn & 31);
                    kdst[chunk + (dh >> 4) * 512 + lane2 * 8 + (dh & 7)] = f2bf(vvv);
                } else {
                    // V fragment-INTERLEAVED: [islot][lane][8el]
                    int lane2 = ((nn >> 3) & 1) * 32 + (dh & 31);
                    int islot = (dh >> 5) * 2 + ((nn >> 4) & 1);
                    vdst[chunk + islot * 512 + lane2 * 8 + (nn & 7)] = f2bf(vvv);
                }
            }
        }
    }
}

// ======== k_gemm1: 128x128 tile, BK=64, deep-phase schedule ========
__global__ __launch_bounds__(512, 2) void k_gemm1(const unsigned short* __restrict__ A,
                                                  const unsigned short* __restrict__ Bt,
                                                  const float* __restrict__ bias,
                                                  float* __restrict__ outp) {
    __shared__ unsigned short lds1[32768];  // A0 @0, A1 @8192, B0 @16384, B1 @24576 (elems)
    const int K = 1024, NT = 16;
    int tid = threadIdx.x;
    int lane = tid & 63, wv = tid >> 6;
    int wm = wv >> 2, wn = wv & 3;            // 2 x 4
    int F = blockIdx.x;
    int L = (F & 7) * 32 + (F >> 3);
    int n0 = (L % 8) * 128;
    int m0 = (L / 8) * 128;
    int bIdx = m0 >> 11;
    int ntok0 = m0 & 2047;

    f32x4 acc[4][2];
#pragma unroll
    for (int i = 0; i < 4; i++)
#pragma unroll
        for (int j = 0; j < 2; j++) {
            f32x4 z; z[0] = 0.f; z[1] = 0.f; z[2] = 0.f; z[3] = 0.f;
            acc[i][j] = z;
        }

    auto stage = [&](int t) {                  // k-tile t == head t
        int p = t & 1;
        const unsigned short* aptr = A + ((size_t)(bIdx * H_ + t) * N_ + ntok0) * DH;
        const unsigned short* bptr = Bt + (size_t)n0 * K + t * 64;
        unsigned short* ab = &lds1[p * 8192];
        unsigned short* bb = &lds1[16384 + p * 8192];
#pragma unroll
        for (int i = 0; i < 2; i++) {
            int u = i * 512 + tid;
            int r = u >> 3, c8 = u & 7;
            int c8s = c8 ^ (r & 7);
            int db = (i * 512 + wv * 64) * 8;
            load_lds16(aptr + (size_t)r * DH + c8s * 8, &ab[db]);
            load_lds16(bptr + (size_t)r * K  + c8s * 8, &bb[db]);
        }
    };

    stage(0);
    stage(1);

    const int ml = lane & 15, ul = lane >> 4;
    bf16x8 afr[4], bfr[2];

#pragma unroll 1
    for (int t = 0; t < NT; ++t) {
        if (t < NT - 1) { VMCNT_ASM(4); }
        else            { VMCNT_ASM(0); }
        __builtin_amdgcn_s_barrier();

        const unsigned short* ab = &lds1[(t & 1) * 8192];
        const unsigned short* bb = &lds1[16384 + (t & 1) * 8192];

#pragma unroll
        for (int kk = 0; kk < 2; ++kk) {
            int ck = ((kk * 4 + ul) ^ (ml & 7)) * 8;
#pragma unroll
            for (int nj = 0; nj < 2; nj++)
                bfr[nj] = *(const bf16x8*)&bb[(wn * 32 + nj * 16 + ml) * 64 + ck];
#pragma unroll
            for (int q = 0; q < 4; q++)
                afr[q] = *(const bf16x8*)&ab[(wm * 64 + q * 16 + ml) * 64 + ck];
            __builtin_amdgcn_s_barrier();
            __builtin_amdgcn_s_setprio(1);
#pragma unroll
            for (int q = 0; q < 4; q++)
#pragma unroll
                for (int nj = 0; nj < 2; nj++)
                    acc[q][nj] = __builtin_amdgcn_mfma_f32_16x16x32_bf16(
                        afr[q], bfr[nj], acc[q][nj], 0, 0, 0);
            __builtin_amdgcn_s_setprio(0);
            __builtin_amdgcn_s_barrier();
        }
        if (t + 2 < NT) stage(t + 2);
    }

    // epilogue  (C/D: col = lane&15, row = (lane>>4)*4 + r)
#pragma unroll
    for (int nj = 0; nj < 2; nj++) {
        int col = n0 + wn * 32 + nj * 16 + ml;
        float bv = bias[col];
#pragma unroll
        for (int mi = 0; mi < 4; mi++) {
            int rbase = m0 + wm * 64 + mi * 16 + (lane >> 4) * 4;
#pragma unroll
            for (int r = 0; r < 4; r++)
                outp[(size_t)(rbase + r) * D_ + col] = acc[mi][nj][r] + bv;
        }
    }
}

// ------- flash attention (r17 best-known): pipelined softmax+PV(t-1) || QK(t) -------
// 512 thr = 8 waves = 4 qsub x 2 kvh, KVBLK=64, V-ring-3, K-ring-2, 80KB LDS,
// 2 blocks/CU. Eight structural variants (r12-r19) all pin ~53us; this is the best.
__global__ __launch_bounds__(512, 2) void k_attn(const unsigned short* __restrict__ qh,
                                                 const unsigned short* __restrict__ ks,
                                                 const unsigned short* __restrict__ vs,
                                                 unsigned short* __restrict__ o) {
    __shared__ unsigned short smem[40960];   // 80 KB
    unsigned short* kb = smem;               // kb + (ring*2 + half)*4096, ring<2
    unsigned short* vb = smem + 16384;       // vb + (ring*2 + half)*4096, ring<3
    float* red = (float*)smem;               // reused for the merge (34816 B)

    int tid = threadIdx.x;
    int lane = tid & 63, wv = tid >> 6;      // wv 0..7
    int qsub = wv >> 1;                      // 0..3
    int kvh  = wv & 1;                       // 0..1
    int F = blockIdx.x;
    int L = (F & 7) * 64 + (F >> 3);
    int bh = L >> 4;
    int q0 = (L & 15) * 128 + qsub * 32;
    int ln = lane & 31, hi = lane >> 5;
    const size_t bhO = (size_t)bh * N_ * DH;

    const unsigned short* qp = qh + bhO;
    bf16x8 qf[4];
#pragma unroll
    for (int kk = 0; kk < 4; kk++)
        qf[kk] = *(const bf16x8*)(qp + (size_t)(q0 + ln) * DH + kk * 16 + hi * 8);

    const unsigned short* kg = ks + (size_t)bh * 131072;
    const unsigned short* vg = vs + (size_t)bh * 131072;

    // staging role: wv 0,1 -> K half0; 2,3 -> K half1; 4,5 -> V half0; 6,7 -> V half1
    int sbuf = wv >> 1;
    int sl   = wv & 1;
    int sh   = sbuf & 1;
    const unsigned short* srcb = ((sbuf >> 1) ? vg : kg) + (size_t)sh * 65536 + sl * 2048;
    auto stageT = [&](int kr, int vr, int t) {
        unsigned short* dstb = (sbuf >> 1)
            ? vb + (vr * 2 + sh) * 4096 + sl * 2048
            : kb + (kr * 2 + sh) * 4096 + sl * 2048;
#pragma unroll
        for (int i = 0; i < 4; i++)
            load_lds16(srcb + (size_t)t * 4096 + i * 512 + lane * 8, dstb + i * 512);
    };

    f32x16 o0, o1, ZEROV;
#pragma unroll
    for (int r = 0; r < 16; r++) { o0[r] = 0.f; o1[r] = 0.f; ZEROV[r] = 0.f; }
    float m = -INFINITY, l = 0.f;

    // softmax + PV of a previously-computed s (sa, sb), V from vB
    auto softmax_pv = [&](const f32x16& sa, const f32x16& sb, const unsigned short* vB) {
        float mx[8];
#pragma unroll
        for (int i = 0; i < 8; i++)
            mx[i] = fmaxf(fmaxf(sa[i], sa[i + 8]), fmaxf(sb[i], sb[i + 8]));
#pragma unroll
        for (int i = 0; i < 4; i++) mx[i] = fmaxf(mx[i], mx[i + 4]);
        float mt = fmaxf(fmaxf(mx[0], mx[2]), fmaxf(mx[1], mx[3]));
        {
            u32x2 sw = __builtin_amdgcn_permlane32_swap(f2u(mt), f2u(mt), false, false);
            mt = fmaxf(u2f(sw[0]), u2f(sw[1]));
        }
        if (!__all(mt <= m + 8.0f)) {   // defer-max: p <= 2^8
            float mn = fmaxf(m, mt);
            float fs = __builtin_amdgcn_exp2f(m - mn);
            m = mn;
            l *= fs;
#pragma unroll
            for (int r = 0; r < 16; r++) { o0[r] *= fs; o1[r] *= fs; }
        }
        float pa[16], pb[16];
#pragma unroll
        for (int r = 0; r < 16; r++) {
            pa[r] = __builtin_amdgcn_exp2f(sa[r] - m);
            pb[r] = __builtin_amdgcn_exp2f(sb[r] - m);
        }
        float sm[8];
#pragma unroll
        for (int i = 0; i < 8; i++) sm[i] = (pa[i] + pa[i + 8]) + (pb[i] + pb[i + 8]);
#pragma unroll
        for (int i = 0; i < 4; i++) sm[i] = sm[i] + sm[i + 4];
        float sum = (sm[0] + sm[2]) + (sm[1] + sm[3]);
        {
            u32x2 sw = __builtin_amdgcn_permlane32_swap(f2u(sum), f2u(sum), false, false);
            sum = u2f(sw[0]) + u2f(sw[1]);
        }
        l += sum;

        unsigned pka[8], pkb[8];
#pragma unroll
        for (int i = 0; i < 8; i++) {
            pka[i] = cvt_pk_bf16(pa[2 * i], pa[2 * i + 1]);
            pkb[i] = cvt_pk_bf16(pb[2 * i], pb[2 * i + 1]);
        }
        u32x2 s0 = __builtin_amdgcn_permlane32_swap(pka[0], pka[2], false, false);
        u32x2 s1 = __builtin_amdgcn_permlane32_swap(pka[1], pka[3], false, false);
        u32x2 s2 = __builtin_amdgcn_permlane32_swap(pka[4], pka[6], false, false);
        u32x2 s3 = __builtin_amdgcn_permlane32_swap(pka[5], pka[7], false, false);
        bf16x8 pf0 = frag_from_u32(s0[0], s1[0], s0[1], s1[1]);  // kv  0..15
        bf16x8 pf1 = frag_from_u32(s2[0], s3[0], s2[1], s3[1]);  // kv 16..31
        s0 = __builtin_amdgcn_permlane32_swap(pkb[0], pkb[2], false, false);
        s1 = __builtin_amdgcn_permlane32_swap(pkb[1], pkb[3], false, false);
        s2 = __builtin_amdgcn_permlane32_swap(pkb[4], pkb[6], false, false);
        s3 = __builtin_amdgcn_permlane32_swap(pkb[5], pkb[7], false, false);
        bf16x8 pf2 = frag_from_u32(s0[0], s1[0], s0[1], s1[1]);  // kv 32..47
        bf16x8 pf3 = frag_from_u32(s2[0], s3[0], s2[1], s3[1]);  // kv 48..63

        bf16x8 vf0, vf1, vf2, vf3;
        vf0 = *(const bf16x8*)&vB[0 * 512 + lane * 8];
        vf1 = *(const bf16x8*)&vB[1 * 512 + lane * 8];
        vf2 = *(const bf16x8*)&vB[2048 + 0 * 512 + lane * 8];
        vf3 = *(const bf16x8*)&vB[2048 + 1 * 512 + lane * 8];
        o0 = __builtin_amdgcn_mfma_f32_32x32x16_bf16(vf0, pf0, o0, 0, 0, 0);
        o0 = __builtin_amdgcn_mfma_f32_32x32x16_bf16(vf1, pf1, o0, 0, 0, 0);
        o0 = __builtin_amdgcn_mfma_f32_32x32x16_bf16(vf2, pf2, o0, 0, 0, 0);
        o0 = __builtin_amdgcn_mfma_f32_32x32x16_bf16(vf3, pf3, o0, 0, 0, 0);
        vf0 = *(const bf16x8*)&vB[2 * 512 + lane * 8];
        vf1 = *(const bf16x8*)&vB[3 * 512 + lane * 8];
        vf2 = *(const bf16x8*)&vB[2048 + 2 * 512 + lane * 8];
        vf3 = *(const bf16x8*)&vB[2048 + 3 * 512 + lane * 8];
        o1 = __builtin_amdgcn_mfma_f32_32x32x16_bf16(vf0, pf0, o1, 0, 0, 0);
        o1 = __builtin_amdgcn_mfma_f32_32x32x16_bf16(vf1, pf1, o1, 0, 0, 0);
        o1 = __builtin_amdgcn_mfma_f32_32x32x16_bf16(vf2, pf2, o1, 0, 0, 0);
        o1 = __builtin_amdgcn_mfma_f32_32x32x16_bf16(vf3, pf3, o1, 0, 0, 0);
    };

    stageT(0, 0, 0);
    __syncthreads();

    f32x16 sa, sb;
#pragma unroll 1
    for (int t = 0; t < 16; ++t) {
        if (t < 15) stageT((t + 1) & 1, (t + 1) % 3, t + 1);

        // softmax + PV of tile t-1 (s regs from last iteration)
        if (t > 0) softmax_pv(sa, sb, vb + (((t - 1) % 3) * 2 + kvh) * 4096);

        // QK^T of tile t (K landed: barrier at end of t-1); C-in = persistent ZERO
        const unsigned short* kB = kb + ((t & 1) * 2 + kvh) * 4096;
        bf16x8 kfa[4], kfb[4];
#pragma unroll
        for (int i = 0; i < 4; i++) {
            kfa[i] = *(const bf16x8*)&kB[i * 512 + lane * 8];
            kfb[i] = *(const bf16x8*)&kB[2048 + i * 512 + lane * 8];
        }
        sa = __builtin_amdgcn_mfma_f32_32x32x16_bf16(kfa[0], qf[0], ZEROV, 0, 0, 0);
#pragma unroll
        for (int i = 1; i < 4; i++)
            sa = __builtin_amdgcn_mfma_f32_32x32x16_bf16(kfa[i], qf[i], sa, 0, 0, 0);
        sb = __builtin_amdgcn_mfma_f32_32x32x16_bf16(kfb[0], qf[0], ZEROV, 0, 0, 0);
#pragma unroll
        for (int i = 1; i < 4; i++)
            sb = __builtin_amdgcn_mfma_f32_32x32x16_bf16(kfb[i], qf[i], sb, 0, 0, 0);

        __syncthreads();   // stage(t+1) landed + all reads of K(t), V(t-1) done
    }
    // epilogue: softmax + PV of tile 15 (V in ring slot 15%3 = 0)
    softmax_pv(sa, sb, vb + (0 * 2 + kvh) * 4096);
    __syncthreads();       // all V reads done before merge overwrites smem

    // ---- merge kv-halves via LDS (exp-weighted, r3-validated) ----
    if (kvh == 1) {
        float* rp = red + (qsub * 64 + lane) * 34;
#pragma unroll
        for (int r = 0; r < 16; r++) { rp[r] = o0[r]; rp[16 + r] = o1[r]; }
        rp[32] = m;
        rp[33] = l;
    }
    __syncthreads();
    if (kvh == 0) {
        const float* rp = red + (qsub * 64 + lane) * 34;
        float mb = rp[32], lb = rp[33];
        float mn = fmaxf(m, mb);
        float fa = __builtin_amdgcn_exp2f(m - mn);
        float fb = __builtin_amdgcn_exp2f(mb - mn);
        float inv = 1.0f / (l * fa + lb * fb);
        float ga = fa * inv, gb = fb * inv;
        unsigned short* ob = o + bhO + (size_t)(q0 + ln) * DH;
#pragma unroll
        for (int t2 = 0; t2 < 2; t2++) {
#pragma unroll
            for (int g = 0; g < 4; g++) {
                int d = t2 * 32 + g * 8 + hi * 4;   // rows: (r&3)+8*(r>>2)+4*hi
                int rb = g * 4;
                float a0 = (t2 ? o1[rb + 0] : o0[rb + 0]) * ga + rp[t2 * 16 + rb + 0] * gb;
                float a1 = (t2 ? o1[rb + 1] : o0[rb + 1]) * ga + rp[t2 * 16 + rb + 1] * gb;
                float a2 = (t2 ? o1[rb + 2] : o0[rb + 2]) * ga + rp[t2 * 16 + rb + 2] * gb;
                float a3 = (t2 ? o1[rb + 3] : o0[rb + 3]) * ga + rp[t2 * 16 + rb + 3] * gb;
                us4 w;
                w.x = f2bf(a0); w.y = f2bf(a1); w.z = f2bf(a2); w.w = f2bf(a3);
                *(us4*)(ob + d) = w;
            }
        }
    }
}

extern "C" void kernel_launch(void* const* d_in, const int* in_sizes, int n_in,
                              void* d_out, int out_size, void* d_ws, size_t ws_size,
                              hipStream_t stream) {
    const float* x  = (const float*)d_in[0];
    const float* W1 = (const float*)d_in[1];
    const float* b1 = (const float*)d_in[2];
    const float* W2 = (const float*)d_in[3];
    const float* b2 = (const float*)d_in[4];
    float* out = (float*)d_out;

    char* ws = (char*)d_ws;
    unsigned short* xb   = (unsigned short*)(ws);                  //  8,388,608 B
    unsigned short* w1t  = (unsigned short*)(ws + 8388608);        //  6,291,456 B
    unsigned short* w2t  = (unsigned short*)(ws + 14680064);       //  2,097,152 B
    unsigned short* qh   = (unsigned short*)(ws + 16777216);       //  8,388,608 B
    unsigned short* ks   = (unsigned short*)(ws + 25165824);       //  8,388,608 B
    unsigned short* vsb  = (unsigned short*)(ws + 33554432);       //  8,388,608 B
    unsigned short* attn = (unsigned short*)(ws + 41943040);       //  8,388,608 B

    k_pre<<<5120, 256, 0, stream>>>(x, xb, W1, w1t, W2, w2t);
    k_gemm0<<<768, 512, 0, stream>>>(xb, w1t, b1, qh, ks, vsb);
    k_attn<<<512, 512, 0, stream>>>(qh, ks, vsb, attn);
    k_gemm1<<<256, 512, 0, stream>>>(attn, w2t, b2, out);
}